// Round 4
// baseline (738.497 us; speedup 1.0000x reference)
//
#include <hip/hip_runtime.h>

#define DD 1024

typedef short short8 __attribute__((ext_vector_type(8)));   // 8 bf16 in 4 VGPRs
typedef float f32x4 __attribute__((ext_vector_type(4)));

__device__ __forceinline__ unsigned short f2bf(float f) {
  unsigned int u = __float_as_uint(f);
  unsigned int r = (u + 0x7FFFu + ((u >> 16) & 1u)) >> 16;   // RNE
  return (unsigned short)r;
}
__device__ __forceinline__ float sigm(float x) { return 1.0f / (1.0f + __expf(-x)); }
__device__ __forceinline__ float tanh_fast(float x) {
  float e = __expf(-2.0f * fabsf(x));
  float t = (1.0f - e) / (1.0f + e);
  return copysignf(t, x);
}
__device__ __forceinline__ void gload_lds16(const void* g, void* l) {
  __builtin_amdgcn_global_load_lds((const __attribute__((address_space(1))) void*)g,
                                   (__attribute__((address_space(3))) void*)l, 16, 0, 0);
}

// ---- one-time weight prep: Wcat[4][1024][1024] bf16, bias[4][1024] f32 ----
__global__ __launch_bounds__(256) void prep_weights(
    const float* __restrict__ Wih, const float* __restrict__ Whh,
    const float* __restrict__ bih, const float* __restrict__ bhh,
    unsigned short* __restrict__ Wcat, float* __restrict__ bias) {
  int i = blockIdx.x * 256 + threadIdx.x;
  int g = i >> 18;
  int rem = i & 262143;
  int n = rem >> 8;
  int k4 = rem & 255;
  const float4* wih4 = reinterpret_cast<const float4*>(Wih);
  const float4* whh4 = reinterpret_cast<const float4*>(Whh);
  float4 v;
  if (g == 0) {
    size_t idx = (size_t)n * 256 + k4;
    float4 a = wih4[idx], b = whh4[idx];
    v = make_float4(a.x + b.x, a.y + b.y, a.z + b.z, a.w + b.w);
  } else if (g == 1) {
    size_t idx = (size_t)(DD + n) * 256 + k4;
    float4 a = wih4[idx], b = whh4[idx];
    v = make_float4(a.x + b.x, a.y + b.y, a.z + b.z, a.w + b.w);
  } else if (g == 2) {
    size_t idx = (size_t)(2 * DD + n) * 256 + k4;
    v = wih4[idx];
  } else {
    size_t idx = (size_t)(2 * DD + n) * 256 + k4;
    v = whh4[idx];
  }
  ushort4 o = make_ushort4(f2bf(v.x), f2bf(v.y), f2bf(v.z), f2bf(v.w));
  reinterpret_cast<ushort4*>(Wcat)[i] = o;

  if (i < 4 * DD) {
    int bg = i >> 10, bn = i & 1023;
    float bv;
    if (bg == 0)      bv = bih[bn] + bhh[bn];
    else if (bg == 1) bv = bih[DD + bn] + bhh[DD + bn];
    else if (bg == 2) bv = bih[2 * DD + bn];
    else              bv = bhh[2 * DD + bn];
    bias[i] = bv;
  }
}

// ---- per-iteration: error GEMV + bf16 cast of state ----
__global__ __launch_bounds__(256) void error_cast(
    const float* S, const float* __restrict__ We, const float* __restrict__ be,
    unsigned short* __restrict__ Sb, float* __restrict__ err) {
  __shared__ float part[4];
  const int row = blockIdx.x;
  const int t = threadIdx.x;
  float4 v = reinterpret_cast<const float4*>(S + (size_t)row * DD)[t];
  float4 w = reinterpret_cast<const float4*>(We)[t];
  float dot = v.x * w.x + v.y * w.y + v.z * w.z + v.w * w.w;
  ushort4 o = make_ushort4(f2bf(v.x), f2bf(v.y), f2bf(v.z), f2bf(v.w));
  reinterpret_cast<ushort4*>(Sb + (size_t)row * DD)[t] = o;
#pragma unroll
  for (int off = 32; off > 0; off >>= 1) dot += __shfl_xor(dot, off);
  if ((t & 63) == 0) part[t >> 6] = dot;
  __syncthreads();
  if (t == 0) err[row] = sigm(part[0] + part[1] + part[2] + part[3] + be[0]);
}

// ---- fused 4-gate GEMM + GRU epilogue, 4-phase/K-tile counted-vmcnt pipeline ----
// Tile 256M x (4g x 64dg), BK=64, 16 K-tiles, 8 waves (2M x 4N), wave 128x64.
// Phase X = { ds_read frags ; stage 2 chunks ; s_barrier ; lgkmcnt(0) ;
//             setprio(1) 16 MFMA setprio(0) ; [vmcnt(2) at D] ; s_barrier }
__global__ __launch_bounds__(512, 2) void gru_fused_gemm(
    const unsigned short* __restrict__ Sb,   // [M][1024] bf16 state
    const unsigned short* __restrict__ Wcat, // [4096][1024] bf16
    const float* __restrict__ bias,          // [4096]
    const float* __restrict__ err,           // [M]
    const float* Sf,                         // [M][1024] f32 h (may alias out)
    float* out, int M) {
  __shared__ alignas(16) unsigned short As[2 * 256 * 64];   // 64 KB (2 slots)
  __shared__ alignas(16) unsigned short Bs[2 * 256 * 64];   // 64 KB (2 slots)

  const int nwg = gridDim.x;
  const int bid = blockIdx.x;
  const int swz = (bid & 7) * (nwg >> 3) + (bid >> 3);
  const int db = swz & 15;
  const int rb = swz >> 4;

  const int tid = threadIdx.x;
  const int w = tid >> 6;
  const int lane = tid & 63;
  const int wr = w >> 2, wc = w & 3;

  // staging: chunks c = w + i*8 (8 rows x 64k, 1 KB each); pre-swizzled src
  // A chunks: i=0 rows 0-63 (h0a), i=1 rows 64-127 (h1a), i=2 128-191 (h0b), i=3 192-255 (h1b)
  const int l8 = lane >> 3;
  const int lkb = ((lane & 7) ^ l8) * 8;
  const unsigned short* srcA[4];
  const unsigned short* srcB[4];
  unsigned short* dstA[4];
  unsigned short* dstB[4];
#pragma unroll
  for (int i = 0; i < 4; ++i) {
    int c = w + i * 8;
    int r = c * 8 + l8;
    srcA[i] = Sb + (size_t)(rb * 256 + r) * DD + lkb;
    int wcq = r >> 6, g = (r >> 4) & 3, dgl = r & 15;
    srcB[i] = Wcat + (size_t)(g * DD + db * 64 + wcq * 16 + dgl) * DD + lkb;
    dstA[i] = As + c * 512;
    dstB[i] = Bs + c * 512;
  }

  const int l15 = lane & 15;
  const int g4 = lane >> 4;
  const int kx = (lane & 7) * 8;
  const int arow0 = (wr * 128 + l15) * 64;
  const int brow0 = (wc * 64 + l15) * 64;

  f32x4 acc[8][4];
#pragma unroll
  for (int mi = 0; mi < 8; ++mi)
#pragma unroll
    for (int g = 0; g < 4; ++g) acc[mi][g] = f32x4{0.f, 0.f, 0.f, 0.f};

  // prologue: tiles 0 and 1 fully staged
#pragma unroll
  for (int i = 0; i < 4; ++i) gload_lds16(srcA[i], dstA[i]);
#pragma unroll
  for (int i = 0; i < 4; ++i) gload_lds16(srcB[i], dstB[i]);
#pragma unroll
  for (int i = 0; i < 4; ++i) gload_lds16(srcA[i] + 64, dstA[i] + 16384);
#pragma unroll
  for (int i = 0; i < 4; ++i) gload_lds16(srcB[i] + 64, dstB[i] + 16384);
  asm volatile("s_waitcnt vmcnt(8)" ::: "memory");
  asm volatile("s_barrier" ::: "memory");

  for (int t = 0; t < 16; ++t) {
    const int sb = (t & 1) * 16384;
    const int sl1 = ((t + 1) & 1) * 16384;
    const int koff1 = (t + 1) * 64;
    const int koff2 = (t + 2) * 64;
    const int k0 = (g4 * 8) ^ kx;
    const int k1 = (32 + g4 * 8) ^ kx;
    const bool stg1 = (t >= 1) && (t <= 14);   // tile t+1 in [2,15]

    // ---------- phase A: kk0, mi 0-3 ----------
    short8 aA[4], bA[4];
#pragma unroll
    for (int i = 0; i < 4; ++i)
      aA[i] = *reinterpret_cast<const short8*>(&As[sb + arow0 + i * 1024 + k0]);
#pragma unroll
    for (int g = 0; g < 4; ++g)
      bA[g] = *reinterpret_cast<const short8*>(&Bs[sb + brow0 + g * 1024 + k0]);
    if (stg1) {                                 // A(t+1).h1
      gload_lds16(srcA[1] + koff1, dstA[1] + sl1);
      gload_lds16(srcA[3] + koff1, dstA[3] + sl1);
    }
    asm volatile("s_barrier" ::: "memory");
    asm volatile("s_waitcnt lgkmcnt(0)" ::: "memory");
    __builtin_amdgcn_s_setprio(1);
#pragma unroll
    for (int g = 0; g < 4; ++g)
#pragma unroll
      for (int mi = 0; mi < 4; ++mi)
        acc[mi][g] = __builtin_amdgcn_mfma_f32_16x16x32_bf16(aA[mi], bA[g], acc[mi][g], 0, 0, 0);
    __builtin_amdgcn_s_setprio(0);
    asm volatile("s_barrier" ::: "memory");

    // ---------- phase B: kk0, mi 4-7 ----------
    short8 aB[4];
#pragma unroll
    for (int i = 0; i < 4; ++i)
      aB[i] = *reinterpret_cast<const short8*>(&As[sb + arow0 + (4 + i) * 1024 + k0]);
    if (stg1) {                                 // B(t+1) p1
      gload_lds16(srcB[0] + koff1, dstB[0] + sl1);
      gload_lds16(srcB[1] + koff1, dstB[1] + sl1);
    }
    asm volatile("s_barrier" ::: "memory");
    asm volatile("s_waitcnt lgkmcnt(0)" ::: "memory");
    __builtin_amdgcn_s_setprio(1);
#pragma unroll
    for (int g = 0; g < 4; ++g)
#pragma unroll
      for (int mi = 0; mi < 4; ++mi)
        acc[4 + mi][g] = __builtin_amdgcn_mfma_f32_16x16x32_bf16(aB[mi], bA[g], acc[4 + mi][g], 0, 0, 0);
    __builtin_amdgcn_s_setprio(0);
    asm volatile("s_barrier" ::: "memory");

    // ---------- phase C: kk1, mi 0-3 ----------
    short8 aC[4], bC[4];
#pragma unroll
    for (int i = 0; i < 4; ++i)
      aC[i] = *reinterpret_cast<const short8*>(&As[sb + arow0 + i * 1024 + k1]);
#pragma unroll
    for (int g = 0; g < 4; ++g)
      bC[g] = *reinterpret_cast<const short8*>(&Bs[sb + brow0 + g * 1024 + k1]);
    if (stg1) {                                 // B(t+1) p2
      gload_lds16(srcB[2] + koff1, dstB[2] + sl1);
      gload_lds16(srcB[3] + koff1, dstB[3] + sl1);
    }
    asm volatile("s_barrier" ::: "memory");
    asm volatile("s_waitcnt lgkmcnt(0)" ::: "memory");
    __builtin_amdgcn_s_setprio(1);
#pragma unroll
    for (int g = 0; g < 4; ++g)
#pragma unroll
      for (int mi = 0; mi < 4; ++mi)
        acc[mi][g] = __builtin_amdgcn_mfma_f32_16x16x32_bf16(aC[mi], bC[g], acc[mi][g], 0, 0, 0);
    __builtin_amdgcn_s_setprio(0);
    asm volatile("s_barrier" ::: "memory");

    // ---------- phase D: kk1, mi 4-7 ----------
    short8 aD[4];
#pragma unroll
    for (int i = 0; i < 4; ++i)
      aD[i] = *reinterpret_cast<const short8*>(&As[sb + arow0 + (4 + i) * 1024 + k1]);
    if (t <= 13) {                              // A(t+2).h0 into slot sb (fully read after C)
      gload_lds16(srcA[0] + koff2, dstA[0] + sb);
      gload_lds16(srcA[2] + koff2, dstA[2] + sb);
    }
    asm volatile("s_barrier" ::: "memory");
    asm volatile("s_waitcnt lgkmcnt(0)" ::: "memory");
    __builtin_amdgcn_s_setprio(1);
#pragma unroll
    for (int g = 0; g < 4; ++g)
#pragma unroll
      for (int mi = 0; mi < 4; ++mi)
        acc[4 + mi][g] = __builtin_amdgcn_mfma_f32_16x16x32_bf16(aD[mi], bC[g], acc[4 + mi][g], 0, 0, 0);
    __builtin_amdgcn_s_setprio(0);
    // certify tile t+1 landed (2 of t+2's loads may stay in flight), then block-wide fence
    if (t < 14)       asm volatile("s_waitcnt vmcnt(2)" ::: "memory");
    else if (t == 14) asm volatile("s_waitcnt vmcnt(0)" ::: "memory");
    asm volatile("s_barrier" ::: "memory");
  }

  // ---- epilogue: r,z,n + out = h + e*(1-z)*(n-h)
  const int mbase = rb * 256 + wr * 128;
  const int dg = db * 64 + wc * 16 + l15;
  const float b_r = bias[dg];
  const float b_z = bias[DD + dg];
  const float b_i = bias[2 * DD + dg];
  const float b_h = bias[3 * DD + dg];
#pragma unroll
  for (int mi = 0; mi < 8; ++mi) {
#pragma unroll
    for (int j = 0; j < 4; ++j) {
      int m = mbase + mi * 16 + g4 * 4 + j;
      float e = err[m];
      float h = Sf[(size_t)m * DD + dg];
      float r = sigm(acc[mi][0][j] + b_r);
      float z = sigm(acc[mi][1][j] + b_z);
      float n = tanh_fast(acc[mi][2][j] + b_i + r * (acc[mi][3][j] + b_h));
      out[(size_t)m * DD + dg] = h + e * (1.0f - z) * (n - h);
    }
  }
}

extern "C" void kernel_launch(void* const* d_in, const int* in_sizes, int n_in,
                              void* d_out, int out_size, void* d_ws, size_t ws_size,
                              hipStream_t stream) {
  const float* x   = (const float*)d_in[0];
  const float* Wih = (const float*)d_in[1];
  const float* Whh = (const float*)d_in[2];
  const float* bih = (const float*)d_in[3];
  const float* bhh = (const float*)d_in[4];
  const float* We  = (const float*)d_in[5];
  const float* be  = (const float*)d_in[6];
  float* out = (float*)d_out;
  const int M = in_sizes[0] / DD;   // 32768

  char* ws = (char*)d_ws;
  unsigned short* Sb   = (unsigned short*)ws;
  unsigned short* Wcat = (unsigned short*)(ws + (size_t)M * DD * 2);
  float* bias = (float*)(ws + (size_t)M * DD * 2 + (size_t)4 * DD * DD * 2);
  float* err  = (float*)(ws + (size_t)M * DD * 2 + (size_t)4 * DD * DD * 2 + (size_t)4 * DD * 4);

  prep_weights<<<4096, 256, 0, stream>>>(Wih, Whh, bih, bhh, Wcat, bias);

  const int nwg = (M / 256) * (DD / 64);   // 2048
  const float* S = x;
  for (int it = 0; it < 2; ++it) {
    error_cast<<<M, 256, 0, stream>>>(S, We, be, Sb, err);
    gru_fused_gemm<<<nwg, 512, 0, stream>>>(Sb, Wcat, bias, err, S, out, M);
    S = out;
  }
}